// Round 8
// baseline (376.395 us; speedup 1.0000x reference)
//
#include <hip/hip_runtime.h>

#define MMOD 8
#define BB 8192
#define DD 256

typedef unsigned short u16;
typedef __attribute__((ext_vector_type(8))) short s16x8;
typedef __attribute__((ext_vector_type(4))) float f32x4;
typedef __attribute__((ext_vector_type(8))) unsigned short u16x8;

typedef __attribute__((address_space(3))) unsigned short lds_u16;
typedef __attribute__((address_space(1))) const unsigned short gl_u16;

__device__ __forceinline__ float b2f(u16 u){ union{unsigned i; float f;} x; x.i=((unsigned)u)<<16; return x.f; }
__device__ __forceinline__ u16 f2b(float f){ union{float f; unsigned i;} x; x.f=f; unsigned r = x.i + 0x7FFF + ((x.i>>16)&1u); return (u16)(r>>16); }

__device__ __forceinline__ void async_cp16(const u16* g, u16* l){
  __builtin_amdgcn_global_load_lds((gl_u16*)g, (lds_u16*)l, 16, 0, 0);
}

// ---------------- fp32 -> bf16 conversion ----------------
struct ConvArgs {
  const float* src[10];
  u16*         dst[10];
  int          n[10];
};
__global__ void convert_kernel(ConvArgs a){
  const long long stride = (long long)gridDim.x * blockDim.x;
  const long long base   = (long long)blockIdx.x * blockDim.x + threadIdx.x;
  for (int s = 0; s < 10; s++){
    const int n  = a.n[s];
    const int n8 = n >> 3;
    const float* sp = a.src[s];
    u16* dst = a.dst[s];
    for (long long i = base; i < n8; i += stride){
      float4 lo = ((const float4*)sp)[i*2];
      float4 hi = ((const float4*)sp)[i*2+1];
      u16x8 p;
      p[0]=f2b(lo.x); p[1]=f2b(lo.y); p[2]=f2b(lo.z); p[3]=f2b(lo.w);
      p[4]=f2b(hi.x); p[5]=f2b(hi.y); p[6]=f2b(hi.z); p[7]=f2b(hi.w);
      *(u16x8*)(dst + (i<<3)) = p;
    }
    for (long long i = ((long long)n8<<3) + base; i < n; i += stride)
      dst[i] = f2b(sp[i]);
  }
}

__device__ __forceinline__ s16x8 load8_f32(const float* p, long long idx){
  float4 lo = *(const float4*)(p + idx);
  float4 hi = *(const float4*)(p + idx + 4);
  s16x8 r;
  r[0]=(short)f2b(lo.x); r[1]=(short)f2b(lo.y); r[2]=(short)f2b(lo.z); r[3]=(short)f2b(lo.w);
  r[4]=(short)f2b(hi.x); r[5]=(short)f2b(hi.y); r[6]=(short)f2b(hi.z); r[7]=(short)f2b(hi.w);
  return r;
}

struct GArgs {
  const u16* A;  long long a_z; long long a_piece; int lda;
  const u16* A2; long long a2_z;
  const u16* B;  long long b_z; int ldb;
  u16*       C;  long long c_z; long long c_npiece; int ldc;
  const u16* bias; long long bias_z;
  const float* cbias;
  float scale;
  int K;
  int relu;
};

// ---------- fat tile: 128x128, BK=64, for the big K=2048 GEMM ----------
__global__ __launch_bounds__(256, 2) void gemm_bt(GArgs g){
  alignas(16) __shared__ u16 lA[128*64];
  alignas(16) __shared__ u16 lB[128*64];
  const int tid  = threadIdx.x;
  const int lane = tid & 63;
  const int w    = tid >> 6;
  const int z    = blockIdx.z;

  const u16* Bbase = g.B + (long long)z * g.b_z + (long long)(blockIdx.y * 128) * g.ldb;

  f32x4 acc[4][4];
  #pragma unroll
  for (int i=0;i<4;i++)
    #pragma unroll
    for (int j=0;j<4;j++)
      #pragma unroll
      for (int r=0;r<4;r++) acc[i][j][r] = 0.0f;

  const int wr = (w >> 1) * 64, wc = (w & 1) * 64;
  const int fm = lane & 15;
  const int fk = (lane >> 4) * 8;
  const long long arow0 = (long long)blockIdx.x * 128;

  const int sr = lane >> 3;
  const int sq = (lane & 7) ^ sr;

  for (int k0 = 0; k0 < g.K; k0 += 64){
    const u16* Abase0 = (g.A2 && k0 >= 256) ? (g.A2 + (long long)z * g.a2_z)
                                            : (g.A  + (long long)z * g.a_z);
    const u16* At = Abase0 + (long long)(k0 >> 8) * g.a_piece + (k0 & 255);
    const u16* Bt = Bbase + k0;
    __syncthreads();
    #pragma unroll
    for (int i=0;i<4;i++){
      int r = i*32 + w*8 + sr;
      async_cp16(At + (arow0 + r) * (long long)g.lda + sq*8, lA + (i*256 + w*64) * 8);
      async_cp16(Bt + (long long)r * g.ldb + sq*8, lB + (i*256 + w*64) * 8);
    }
    __syncthreads();
    #pragma unroll
    for (int kk = 0; kk < 64; kk += 32){
      s16x8 af[4], bfr[4];
      const int qf = (kk + fk) >> 3;
      #pragma unroll
      for (int mi=0; mi<4; mi++){
        int r = wr + mi*16 + fm;
        af[mi] = *(const s16x8*)(lA + (r*8 + (qf ^ (r & 7))) * 8);
      }
      #pragma unroll
      for (int ni=0; ni<4; ni++){
        int r = wc + ni*16 + fm;
        bfr[ni] = *(const s16x8*)(lB + (r*8 + (qf ^ (r & 7))) * 8);
      }
      #pragma unroll
      for (int mi=0; mi<4; mi++)
        #pragma unroll
        for (int ni=0; ni<4; ni++)
          acc[mi][ni] = __builtin_amdgcn_mfma_f32_16x16x32_bf16(af[mi], bfr[ni], acc[mi][ni], 0, 0, 0);
    }
  }

  u16* Cb = g.C + (long long)z * g.c_z;
  const u16* biasp = g.bias ? g.bias + (long long)z * g.bias_z : (const u16*)0;
  #pragma unroll
  for (int mi=0; mi<4; mi++){
    #pragma unroll
    for (int ni=0; ni<4; ni++){
      int n = blockIdx.y*128 + wc + ni*16 + fm;
      float bb = 0.0f;
      if (g.cbias) bb = g.cbias[n];
      else if (biasp) bb = b2f(biasp[n]);
      long long cn = ((long long)(n >> 8)) * g.c_npiece + (n & 255);
      #pragma unroll
      for (int r=0; r<4; r++){
        long long b = arow0 + wr + mi*16 + (lane>>4)*4 + r;
        float v = acc[mi][ni][r] * g.scale + bb;
        if (g.relu) v = v > 0.0f ? v : 0.0f;
        Cb[cn + b * (long long)g.ldc] = f2b(v);
      }
    }
  }
}

// ---------- fused MLP + controller: 64-row strip x one modality per block ----------
// phase1: hid = relu([xb|cross]@W1^T + b1)   K=512 -> LDS stage
// phase2: fused = hid@W2^T + b2              K=256 -> HBM + LDS stage
// phase3: ch = relu([q|fused]@Wc1^T + bc1)   K=512 -> wc2 dot -> sigmoid -> scores
struct MArgs {
  const u16 *xb, *cross, *qb, *W1, *W2, *Wc1;
  const u16 *b1, *b2, *bc1, *wc2;
  const float* bc2;
  u16* fused;
  float* scores;
};
__global__ __launch_bounds__(256, 2) void gemm_mlp(MArgs g){
  alignas(16) __shared__ u16 lA[64*64];         // 8KB rotating A tile
  alignas(16) __shared__ u16 lB[256*64];        // 32KB B tile
  alignas(16) __shared__ u16 stage[4][64*64];   // 32KB staging (hid, then fused)
  const int tid  = threadIdx.x;
  const int lane = tid & 63;
  const int w    = tid >> 6;
  const int m    = blockIdx.z;
  const int fm   = lane & 15;
  const int fk   = (lane >> 4) * 8;
  const int sr   = lane >> 3;
  const int sq   = (lane & 7) ^ sr;
  const long long arow0 = (long long)blockIdx.x * 64;
  const long long BD = (long long)BB * DD;

  f32x4 acc[16];
  #pragma unroll
  for (int j=0;j<16;j++)
    #pragma unroll
    for (int r=0;r<4;r++) acc[j][r] = 0.0f;

  const int ra = w*16 + fm;
  const int myrow = w*16 + (lane>>4)*4;   // +r

  // ---- Phase 1: K=512 over [xb | cross], B = W1[m] (256x512)
  for (int t = 0; t < 8; t++){
    const int k0 = t*64;
    const u16* At = (t < 4 ? g.xb : g.cross) + (long long)m * BD + (k0 & 255);
    const u16* Bt = g.W1 + (long long)m * 131072 + k0;
    __syncthreads();
    #pragma unroll
    for (int i=0;i<2;i++){
      int r = i*32 + w*8 + sr;
      async_cp16(At + (arow0 + r) * 256LL + sq*8, lA + (i*256 + w*64) * 8);
    }
    #pragma unroll
    for (int i=0;i<8;i++){
      int r = i*32 + w*8 + sr;
      async_cp16(Bt + (long long)r * 512 + sq*8, lB + (i*256 + w*64) * 8);
    }
    __syncthreads();
    #pragma unroll
    for (int kk = 0; kk < 64; kk += 32){
      const int qf = (kk + fk) >> 3;
      s16x8 af = *(const s16x8*)(lA + (ra*8 + (qf ^ (ra & 7))) * 8);
      #pragma unroll
      for (int ni=0; ni<16; ni++){
        int r = ni*16 + fm;
        s16x8 bfr = *(const s16x8*)(lB + (r*8 + (qf ^ (r & 7))) * 8);
        acc[ni] = __builtin_amdgcn_mfma_f32_16x16x32_bf16(af, bfr, acc[ni], 0, 0, 0);
      }
    }
  }
  // hid -> stage (relu + b1). element (row, n): tile t=n>>6, k=n&63
  #pragma unroll
  for (int ni=0; ni<16; ni++){
    int n = ni*16 + fm;
    float bb = b2f(g.b1[m*256 + n]);
    int t = ni >> 2, k = n & 63, q = k >> 3, j = k & 7;
    #pragma unroll
    for (int r=0; r<4; r++){
      int row = myrow + r;
      float v = acc[ni][r] + bb;
      v = v > 0.0f ? v : 0.0f;
      stage[t][(row*8 + (q ^ (row & 7)))*8 + j] = f2b(v);
    }
  }
  #pragma unroll
  for (int j=0;j<16;j++)
    #pragma unroll
    for (int r=0;r<4;r++) acc[j][r] = 0.0f;
  __syncthreads();

  // ---- Phase 2: K=256, A = stage (hid), B = W2[m] (256x256)
  for (int t = 0; t < 4; t++){
    const int k0 = t*64;
    const u16* Bt = g.W2 + (long long)m * 65536 + k0;
    __syncthreads();
    #pragma unroll
    for (int i=0;i<8;i++){
      int r = i*32 + w*8 + sr;
      async_cp16(Bt + (long long)r * 256 + sq*8, lB + (i*256 + w*64) * 8);
    }
    __syncthreads();
    #pragma unroll
    for (int kk = 0; kk < 64; kk += 32){
      const int qf = (kk + fk) >> 3;
      s16x8 af = *(const s16x8*)(&stage[t][(ra*8 + (qf ^ (ra & 7))) * 8]);
      #pragma unroll
      for (int ni=0; ni<16; ni++){
        int r = ni*16 + fm;
        s16x8 bfr = *(const s16x8*)(lB + (r*8 + (qf ^ (r & 7))) * 8);
        acc[ni] = __builtin_amdgcn_mfma_f32_16x16x32_bf16(af, bfr, acc[ni], 0, 0, 0);
      }
    }
  }
  // fused = acc + b2 -> HBM; all waves done reading stage(hid) before overwrite
  u16 fv[16][4];
  #pragma unroll
  for (int ni=0; ni<16; ni++){
    int n = ni*16 + fm;
    float bb = b2f(g.b2[m*256 + n]);
    #pragma unroll
    for (int r=0; r<4; r++){
      long long b = arow0 + myrow + r;
      u16 h = f2b(acc[ni][r] + bb);
      fv[ni][r] = h;
      g.fused[(long long)m * BD + b*256 + n] = h;
    }
  }
  __syncthreads();
  #pragma unroll
  for (int ni=0; ni<16; ni++){
    int n = ni*16 + fm;
    int t = ni >> 2, k = n & 63, q = k >> 3, j = k & 7;
    #pragma unroll
    for (int r=0; r<4; r++){
      int row = myrow + r;
      stage[t][(row*8 + (q ^ (row & 7)))*8 + j] = fv[ni][r];
    }
  }
  #pragma unroll
  for (int j=0;j<16;j++)
    #pragma unroll
    for (int r=0;r<4;r++) acc[j][r] = 0.0f;
  __syncthreads();

  // ---- Phase 3: K=512, A = [q (k<256) | fused (k>=256)], B = Wc1 (256x512)
  for (int t = 0; t < 8; t++){
    const int k0 = t*64;
    const u16* Bt = g.Wc1 + k0;
    __syncthreads();
    if (t < 4){
      #pragma unroll
      for (int i=0;i<2;i++){
        int r = i*32 + w*8 + sr;
        async_cp16(g.qb + (arow0 + r) * 256LL + k0 + sq*8, lA + (i*256 + w*64) * 8);
      }
    }
    #pragma unroll
    for (int i=0;i<8;i++){
      int r = i*32 + w*8 + sr;
      async_cp16(Bt + (long long)r * 512 + sq*8, lB + (i*256 + w*64) * 8);
    }
    __syncthreads();
    #pragma unroll
    for (int kk = 0; kk < 64; kk += 32){
      const int qf = (kk + fk) >> 3;
      s16x8 af = (t < 4) ? *(const s16x8*)(lA + (ra*8 + (qf ^ (ra & 7))) * 8)
                         : *(const s16x8*)(&stage[t-4][(ra*8 + (qf ^ (ra & 7))) * 8]);
      #pragma unroll
      for (int ni=0; ni<16; ni++){
        int r = ni*16 + fm;
        s16x8 bfr = *(const s16x8*)(lB + (r*8 + (qf ^ (r & 7))) * 8);
        acc[ni] = __builtin_amdgcn_mfma_f32_16x16x32_bf16(af, bfr, acc[ni], 0, 0, 0);
      }
    }
  }
  // controller epilogue: relu(+bc1) -> dot wc2 -> sigmoid -> scores
  float p[4] = {0.f, 0.f, 0.f, 0.f};
  #pragma unroll
  for (int ni=0; ni<16; ni++){
    int n = ni*16 + fm;
    float bb = b2f(g.bc1[n]);
    float wcv = b2f(g.wc2[n]);
    #pragma unroll
    for (int r=0; r<4; r++){
      float v = acc[ni][r] + bb;
      v = v > 0.0f ? v : 0.0f;
      p[r] += v * wcv;
    }
  }
  #pragma unroll
  for (int r=0; r<4; r++){
    #pragma unroll
    for (int off=1; off<16; off<<=1) p[r] += __shfl_xor(p[r], off);
  }
  if (fm == 0){
    float bc2v = g.bc2[0];
    #pragma unroll
    for (int r=0; r<4; r++){
      long long b = arow0 + myrow + r;
      g.scores[(long long)m*BB + b] = 1.0f / (1.0f + __expf(-(p[r] + bc2v)));
    }
  }
}

// WB[n=(s*256+o)][k=(t*256+d)] = sum_e Wo[s,t,o,e]*Wv[s,t,e,d], zeroed on s==t diagonal.
__global__ __launch_bounds__(256, 2) void build_wb(const float* Wo, const float* Wv, u16* WB){
  alignas(16) __shared__ u16 lA[128*64];
  alignas(16) __shared__ u16 lB[128*64];
  const int tid  = threadIdx.x;
  const int lane = tid & 63;
  const int w    = tid >> 6;
  const int z = blockIdx.z, s = z >> 3, t = z & 7;
  const long long zoff = (long long)z * 65536;

  f32x4 acc[4][4];
  #pragma unroll
  for (int i=0;i<4;i++)
    #pragma unroll
    for (int j=0;j<4;j++)
      #pragma unroll
      for (int r=0;r<4;r++) acc[i][j][r] = 0.0f;

  const int wr = (w >> 1) * 64, wc = (w & 1) * 64;
  const int fm = lane & 15;
  const int fk = (lane >> 4) * 8;

  int srow[4], sq[4];
  #pragma unroll
  for (int i=0;i<4;i++){
    int c = i*256 + tid;
    srow[i] = c >> 3;
    sq[i]   = (c & 7) ^ (srow[i] & 7);
  }

  for (int k0 = 0; k0 < 256; k0 += 64){
    s16x8 va[4], vt[4];
    #pragma unroll
    for (int i=0;i<4;i++){
      long long aidx = zoff + (long long)(blockIdx.x*128 + srow[i]) * 256 + k0 + sq[i]*8;
      va[i] = load8_f32(Wo, aidx);
    }
    #pragma unroll
    for (int j=0;j<4;j++){
      int id = j*256 + tid;
      int e  = id >> 4;
      int dc = (id & 15) * 8;
      long long bidx = zoff + (long long)(k0 + e) * 256 + blockIdx.y*128 + dc;
      vt[j] = load8_f32(Wv, bidx);
    }
    __syncthreads();
    #pragma unroll
    for (int i=0;i<4;i++){
      int c = i*256 + tid;
      *(s16x8*)(lA + c*8) = va[i];
    }
    #pragma unroll
    for (int j=0;j<4;j++){
      int id = j*256 + tid;
      int e  = id >> 4;
      int dc = (id & 15) * 8;
      #pragma unroll
      for (int u=0; u<8; u++){
        int d = dc + u;
        lB[(d*8 + ((e>>3) ^ (d & 7)))*8 + (e & 7)] = (u16)vt[j][u];
      }
    }
    __syncthreads();
    #pragma unroll
    for (int kk = 0; kk < 64; kk += 32){
      s16x8 af[4], bfr[4];
      const int qf = (kk + fk) >> 3;
      #pragma unroll
      for (int mi=0; mi<4; mi++){
        int r = wr + mi*16 + fm;
        af[mi] = *(const s16x8*)(lA + (r*8 + (qf ^ (r & 7))) * 8);
      }
      #pragma unroll
      for (int ni=0; ni<4; ni++){
        int r = wc + ni*16 + fm;
        bfr[ni] = *(const s16x8*)(lB + (r*8 + (qf ^ (r & 7))) * 8);
      }
      #pragma unroll
      for (int mi=0; mi<4; mi++)
        #pragma unroll
        for (int ni=0; ni<4; ni++)
          acc[mi][ni] = __builtin_amdgcn_mfma_f32_16x16x32_bf16(af[mi], bfr[ni], acc[mi][ni], 0, 0, 0);
    }
    __syncthreads();
  }
  const int diag = (s == t);
  #pragma unroll
  for (int mi=0; mi<4; mi++){
    #pragma unroll
    for (int ni=0; ni<4; ni++){
      int d = blockIdx.y*128 + wc + ni*16 + fm;
      #pragma unroll
      for (int r=0; r<4; r++){
        int o = blockIdx.x*128 + wr + mi*16 + (lane>>4)*4 + r;
        float v = diag ? 0.0f : acc[mi][ni][r];
        WB[(long long)(s*256 + o) * 2048 + t*256 + d] = f2b(v);
      }
    }
  }
}

// cb[s*256+row] = (1/7) sum_{t!=s}( dot(bv[s,t,:], Wo[s,t,row,:]) + bo[s,t,row] )
// grid (8, 4): block = (s, 64-row chunk); wave-per-16-rows; no atomics, no memset.
__global__ __launch_bounds__(256) void cb_kernel(const float* bv, const float* Wo, const float* bo, float* cb){
  int s = blockIdx.x;
  int lane = threadIdx.x & 63, w = threadIdx.x >> 6;
  #pragma unroll
  for (int i=0; i<16; i++){
    int row = blockIdx.y*64 + w*16 + i;
    float accv = 0.0f;
    for (int t=0; t<8; t++){
      if (t == s) continue;
      int z = s*8 + t;
      float4 bvv = *(const float4*)(bv + (long long)z*256 + lane*4);
      float4 wv4 = *(const float4*)(Wo + (long long)z*65536 + (long long)row*256 + lane*4);
      accv += wv4.x*bvv.x + wv4.y*bvv.y + wv4.z*bvv.z + wv4.w*bvv.w;
    }
    #pragma unroll
    for (int off=32; off>0; off>>=1) accv += __shfl_xor(accv, off);
    if (lane == 0){
      float bsum = 0.0f;
      for (int t=0; t<8; t++){
        if (t == s) continue;
        bsum += bo[(long long)(s*8+t)*256 + row];
      }
      cb[s*256 + row] = (accv + bsum) * (1.0f/7.0f);
    }
  }
}

// out[b,:] = (1/8) sum_m fused[m,b,:] * scores[m,b]
__global__ __launch_bounds__(256) void final_gate(const u16* fused, const float* scores, float* out){
  int b = blockIdx.x;
  int tid = threadIdx.x;
  float sc[8];
  #pragma unroll
  for (int m=0; m<8; m++) sc[m] = scores[(long long)m*BB + b];
  float acc = 0.0f;
  #pragma unroll
  for (int m=0; m<8; m++)
    acc += b2f(fused[((long long)m*BB + b)*256 + tid]) * sc[m];
  out[(long long)b*256 + tid] = acc * 0.125f;
}

extern "C" void kernel_launch(void* const* d_in, const int* in_sizes, int n_in,
                              void* d_out, int out_size, void* d_ws, size_t ws_size,
                              hipStream_t stream){
  const float* x   = (const float*)d_in[0];
  const float* q   = (const float*)d_in[1];
  const float* Wv  = (const float*)d_in[2];
  const float* bv  = (const float*)d_in[3];
  const float* Wo  = (const float*)d_in[4];
  const float* bo  = (const float*)d_in[5];
  const float* W1  = (const float*)d_in[6];
  const float* b1  = (const float*)d_in[7];
  const float* W2  = (const float*)d_in[8];
  const float* b2  = (const float*)d_in[9];
  const float* Wc1 = (const float*)d_in[10];
  const float* bc1 = (const float*)d_in[11];
  const float* wc2 = (const float*)d_in[12];
  const float* bc2 = (const float*)d_in[13];

  char* ws = (char*)d_ws;
  u16*   xb    = (u16*)(ws + 0LL);            // 32MB
  u16*   qb    = (u16*)(ws + 33554432LL);     // 4MB
  u16*   cross = (u16*)(ws + 37748736LL);     // 32MB
  u16*   fused = (u16*)(ws + 71303168LL);     // 32MB
  u16*   WB    = (u16*)(ws + 104857600LL);    // 8MB
  u16*   W1b   = (u16*)(ws + 113246208LL);    // 2MB
  u16*   W2b   = (u16*)(ws + 115343360LL);    // 1MB
  u16*   Wc1b  = (u16*)(ws + 116391936LL);    // 256KB
  u16*   b1b   = (u16*)(ws + 116654080LL);    // 4KB
  u16*   b2b   = (u16*)(ws + 116658176LL);    // 4KB
  u16*   bc1b  = (u16*)(ws + 116662272LL);    // 512B
  u16*   wc2b  = (u16*)(ws + 116662784LL);    // 512B
  float* scores= (float*)(ws + 116663424LL);  // 256KB
  float* cb    = (float*)(ws + 116925568LL);  // 8KB

  ConvArgs ca{};
  ca.src[0]=x;   ca.dst[0]=xb;   ca.n[0]=MMOD*BB*DD;
  ca.src[1]=q;   ca.dst[1]=qb;   ca.n[1]=BB*DD;
  ca.src[2]=W1;  ca.dst[2]=W1b;  ca.n[2]=MMOD*DD*2*DD;
  ca.src[3]=W2;  ca.dst[3]=W2b;  ca.n[3]=MMOD*DD*DD;
  ca.src[4]=Wc1; ca.dst[4]=Wc1b; ca.n[4]=DD*2*DD;
  ca.src[5]=b1;  ca.dst[5]=b1b;  ca.n[5]=MMOD*DD;
  ca.src[6]=b2;  ca.dst[6]=b2b;  ca.n[6]=MMOD*DD;
  ca.src[7]=bc1; ca.dst[7]=bc1b; ca.n[7]=DD;
  ca.src[8]=wc2; ca.dst[8]=wc2b; ca.n[8]=DD;
  ca.src[9]=wc2; ca.dst[9]=wc2b; ca.n[9]=0;   // unused slot
  convert_kernel<<<1024, 256, 0, stream>>>(ca);

  build_wb<<<dim3(2,2,64), 256, 0, stream>>>(Wo, Wv, WB);
  cb_kernel<<<dim3(8,4), 256, 0, stream>>>(bv, Wo, bo, cb);

  const long long BD = (long long)BB * DD;

  // Stage 2 (fat): cross[s,b,o] = (1/7) sum_k xb'[b,k] * WB[(s,o),k] + cb
  GArgs g2{};
  g2.A = xb; g2.a_z = 0; g2.a_piece = BD; g2.lda = 256; g2.A2 = 0; g2.a2_z = 0;
  g2.B = WB; g2.b_z = 0; g2.ldb = 2048;
  g2.C = cross; g2.c_z = 0; g2.c_npiece = BD; g2.ldc = 256;
  g2.bias = 0; g2.bias_z = 0; g2.cbias = cb;
  g2.scale = 1.0f/7.0f; g2.K = 2048; g2.relu = 0;
  gemm_bt<<<dim3(64,16,1), 256, 0, stream>>>(g2);

  // Stages 3+4+5 fused
  MArgs gm{};
  gm.xb = xb; gm.cross = cross; gm.qb = qb;
  gm.W1 = W1b; gm.W2 = W2b; gm.Wc1 = Wc1b;
  gm.b1 = b1b; gm.b2 = b2b; gm.bc1 = bc1b; gm.wc2 = wc2b;
  gm.bc2 = bc2;
  gm.fused = fused; gm.scores = scores;
  gemm_mlp<<<dim3(128,1,8), 256, 0, stream>>>(gm);

  final_gate<<<dim3(BB), 256, 0, stream>>>(fused, scores, (float*)d_out);

  (void)in_sizes; (void)n_in; (void)out_size; (void)ws_size;
}